// Round 8
// baseline (3913.222 us; speedup 1.0000x reference)
//
#include <hip/hip_runtime.h>
#include <float.h>

// RVQ inference via MFMA: B=16, C=64, N=4096, Q=8, K=8192, fp32 in/out.
// bf16 hi/lo split distance GEMM (hh+hl+lh, fp32 acc) on mfma_f32_16x16x32_bf16.
// Round-8: occupancy push. Evidence R1-R7: pipe util tracks resident waves;
// 2 waves/SIMD caps MfmaUtil ~40%. So:
//  - P=64 points/block, grid 1024 = 4 blocks/CU, T=2 ptiles/wave
//    (2-way k x 2-way point split, R6 math) -> VGPR demand ~110 -> 4 waves/SIMD,
//    16 waves/CU, all blocks resident, zero tail, zero spills.
//  - kloop manually 2x ping-pong unrolled: kills ~36 reg copies/ktile.
//  - Packed-index top-2 (12-bit local k in mantissa LSBs, fmed3+fmax),
//    TAU=0.05 exact-fp32 rescore net (passed R5-R7).
// ws: shalf (QK f32) | WH (QKC bf16-hi u16) | WL (lo) | loss (f32).

typedef float f32x4 __attribute__((ext_vector_type(4)));
typedef short s16x8 __attribute__((ext_vector_type(8)));

constexpr int Bn=16, Cn=64, Nn=4096, Qn=8, Kn=8192;
constexpr int P=64;                     // points per block
constexpr int NBLK = Bn*Nn/P;           // 1024 blocks = 4/CU
constexpr float TAU = 0.05f;            // rescore margin
constexpr size_t SH_F = (size_t)Qn*Kn;
constexpr size_t W_U  = (size_t)Qn*Kn*Cn;

union U8 { s16x8 v; unsigned short u[8]; };

__device__ __forceinline__ unsigned short bf_rtne(float x){
  unsigned int u = __float_as_uint(x);
  unsigned int r = (u + 0x7fffu + ((u>>16)&1u)) >> 16;
  return (unsigned short)r;
}

__global__ __launch_bounds__(256) void prep_kernel(const float* __restrict__ cb,
    float* __restrict__ shalf, unsigned short* __restrict__ WH,
    unsigned short* __restrict__ WL, float* __restrict__ loss){
  int r = blockIdx.x*256 + threadIdx.x;
  if (r==0) *loss = 0.f;
  const float* row = cb + (size_t)r*Cn;
  float sq = 0.f;
  for (int c=0;c<Cn;++c){
    float v = row[c]; sq = fmaf(v,v,sq);
    unsigned short h = bf_rtne(v);
    float hf = __uint_as_float((unsigned int)h<<16);
    unsigned short l = bf_rtne(v-hf);
    WH[(size_t)r*Cn+c]=h; WL[(size_t)r*Cn+c]=l;
  }
  shalf[r] = -0.5f*sq;
}

#define LOADK(NK, H0,H1,L0,L1,SV) \
  H0 = *(const s16x8*)(WHq + (size_t)((NK)+l16)*Cn + quad*8); \
  H1 = *(const s16x8*)(WHq + (size_t)((NK)+l16)*Cn + 32 + quad*8); \
  L0 = *(const s16x8*)(WLq + (size_t)((NK)+l16)*Cn + quad*8); \
  L1 = *(const s16x8*)(WLq + (size_t)((NK)+l16)*Cn + 32 + quad*8); \
  SV = *(const f32x4*)(sqq + (NK) + kq);

#define COMPUTE(H0,H1,L0,L1,SV,KB) { \
  f32x4 a0, a1; \
  a0 = __builtin_amdgcn_mfma_f32_16x16x32_bf16(H0, Bh[0][0], SV, 0,0,0); \
  a1 = __builtin_amdgcn_mfma_f32_16x16x32_bf16(H0, Bh[1][0], SV, 0,0,0); \
  a0 = __builtin_amdgcn_mfma_f32_16x16x32_bf16(H0, Bl[0][0], a0, 0,0,0); \
  a1 = __builtin_amdgcn_mfma_f32_16x16x32_bf16(H0, Bl[1][0], a1, 0,0,0); \
  a0 = __builtin_amdgcn_mfma_f32_16x16x32_bf16(L0, Bh[0][0], a0, 0,0,0); \
  a1 = __builtin_amdgcn_mfma_f32_16x16x32_bf16(L0, Bh[1][0], a1, 0,0,0); \
  a0 = __builtin_amdgcn_mfma_f32_16x16x32_bf16(H1, Bh[0][1], a0, 0,0,0); \
  a1 = __builtin_amdgcn_mfma_f32_16x16x32_bf16(H1, Bh[1][1], a1, 0,0,0); \
  a0 = __builtin_amdgcn_mfma_f32_16x16x32_bf16(H1, Bl[0][1], a0, 0,0,0); \
  a1 = __builtin_amdgcn_mfma_f32_16x16x32_bf16(H1, Bl[1][1], a1, 0,0,0); \
  a0 = __builtin_amdgcn_mfma_f32_16x16x32_bf16(L1, Bh[0][1], a0, 0,0,0); \
  a1 = __builtin_amdgcn_mfma_f32_16x16x32_bf16(L1, Bh[1][1], a1, 0,0,0); \
  const unsigned kloc = (unsigned)((KB) & 4095) | (unsigned)kq; \
  _Pragma("unroll") \
  for (int r=0;r<4;++r){ \
    float pv0 = __uint_as_float((__float_as_uint(a0[r]) & 0xFFFFF000u) \
                                | (kloc + (unsigned)r)); \
    float pv1 = __uint_as_float((__float_as_uint(a1[r]) & 0xFFFFF000u) \
                                | (kloc + (unsigned)r)); \
    float n20 = __builtin_amdgcn_fmed3f(pv0, s1[0], s2[0]); \
    s1[0] = fmaxf(s1[0], pv0); s2[0] = n20; \
    float n21 = __builtin_amdgcn_fmed3f(pv1, s1[1], s2[1]); \
    s1[1] = fmaxf(s1[1], pv1); s2[1] = n21; \
  } }

__global__ __launch_bounds__(256,1)
void rvq_kernel(
    const float* __restrict__ x, const float* __restrict__ cb,
    const float* __restrict__ shalf,
    const unsigned short* __restrict__ WH, const unsigned short* __restrict__ WL,
    float* __restrict__ out, float* __restrict__ loss_acc){
  __shared__ float4 RES4[P*16];          // res[p][4g..] at [p*16 + (g^(p&15))]
  __shared__ float  red_p1[4][32];       // packed (score|k12): [wave][pt-in-half]
  __shared__ float  red_p2[4][32];
  __shared__ int    bk_sh[P];
  __shared__ float  lsum[4];

  const int tid  = threadIdx.x;
  const int wave = tid>>6, lane = tid&63;
  const int quad = lane>>4, l16 = lane&15;
  const int kh   = wave & 1;             // code half: [kh*4096, +4096)
  const int ph   = wave >> 1;            // point half: [ph*32, +32)
  const int b    = blockIdx.x>>6;        // 64 blocks per batch elem
  const int n0   = (blockIdx.x&63)*P;

  { // ---- RES init from x[B,C,N] (coalesced over p) ----
#pragma unroll
    for (int it=0; it<4; ++it){
      int f = tid + it*256;              // 1024 float4s
      int p = f & 63, g = f >> 6;
      const float* xb = x + ((size_t)b*Cn)*Nn + n0 + p;
      float4 v;
      v.x = xb[(size_t)(4*g+0)*Nn]; v.y = xb[(size_t)(4*g+1)*Nn];
      v.z = xb[(size_t)(4*g+2)*Nn]; v.w = xb[(size_t)(4*g+3)*Nn];
      RES4[p*16 + (g ^ (p&15))] = v;
    }
  }
  __syncthreads();

  float loss_pt = 0.f;

  for (int q=0;q<Qn;++q){
    const unsigned short* WHq = WH + (size_t)q*Kn*Cn;
    const unsigned short* WLq = WL + (size_t)q*Kn*Cn;
    const float* sqq = shalf + (size_t)q*Kn;

    // ---- B-frags: 2 ptiles x 2 Khalves x hi/lo = 32 VGPRs, resident ----
    s16x8 Bh[2][2], Bl[2][2];
#pragma unroll
    for (int pt=0; pt<2; ++pt){
      int p = ph*32 + pt*16 + l16;
#pragma unroll
      for (int s=0;s<2;++s){
        int g0 = 8*s + quad*2;
        float4 ra = RES4[p*16 + ((g0  ) ^ (p&15))];
        float4 rb = RES4[p*16 + ((g0+1) ^ (p&15))];
        float f[8] = {ra.x,ra.y,ra.z,ra.w, rb.x,rb.y,rb.z,rb.w};
        U8 h, lo;
#pragma unroll
        for (int j=0;j<8;++j){
          unsigned short hu = bf_rtne(f[j]);
          float hf = __uint_as_float((unsigned int)hu<<16);
          h.u[j]=hu; lo.u[j]=bf_rtne(f[j]-hf);
        }
        Bh[pt][s]=h.v; Bl[pt][s]=lo.v;
      }
    }

    // ---- scan this wave's 4096-code half; packed top-2 per point ----
    float s1[2], s2[2];
    s1[0]=-FLT_MAX; s2[0]=-FLT_MAX; s1[1]=-FLT_MAX; s2[1]=-FLT_MAX;

    const int kq = quad*4;
    const int kbase = kh*4096;
    s16x8 Ah0,Ah1,Al0,Al1; f32x4 sv;        // even-step regs
    s16x8 Xh0,Xh1,Xl0,Xl1; f32x4 xv;        // odd-step regs
    LOADK(kbase, Ah0,Ah1,Al0,Al1,sv)

    for (int kt2=0; kt2<128; ++kt2){
      const int ka = kbase + (kt2*2+1)*16;            // odd ktile (always valid)
      LOADK(ka, Xh0,Xh1,Xl0,Xl1,xv)
      COMPUTE(Ah0,Ah1,Al0,Al1,sv, kbase + kt2*2*16)
      const int kbn = kbase + ((kt2*2+2) & 255)*16;   // next even (wraps at end)
      LOADK(kbn, Ah0,Ah1,Al0,Al1,sv)
      COMPUTE(Xh0,Xh1,Xl0,Xl1,xv, ka)
    }

    // ---- cross-quad top-2 merge in packed domain ----
#pragma unroll
    for (int pt=0;pt<2;++pt){
#pragma unroll
      for (int m=16; m<=32; m<<=1){
        float o1 = __shfl_xor(s1[pt], m, 64);
        float o2 = __shfl_xor(s2[pt], m, 64);
        float n1 = fmaxf(s1[pt], o1);
        float n2 = fmaxf(fminf(s1[pt], o1), fmaxf(s2[pt], o2));
        s1[pt]=n1; s2[pt]=n2;
      }
      if (quad==0){
        red_p1[wave][pt*16 + l16] = s1[pt];
        red_p2[wave][pt*16 + l16] = s2[pt];
      }
    }
    __syncthreads();

    // ---- per-point merge of the 2 k-half waves + margin rescore ----
    if (tid < P){
      int ph2 = tid >> 5, pl = tid & 31;
      float S1 = red_p1[2*ph2][pl]; int W1 = 0;
      float S2 = red_p2[2*ph2][pl]; int W2 = 0;
      float o1 = red_p1[2*ph2+1][pl], o2 = red_p2[2*ph2+1][pl];
      if (o1 > S1){
        if (S1 > o2){ S2 = S1; W2 = W1; } else { S2 = o2; W2 = 1; }
        S1 = o1; W1 = 1;
      } else if (o1 > S2){ S2 = o1; W2 = 1; }
      int K1 = (W1<<12) | (int)(__float_as_uint(S1) & 4095u);
      int K2 = (W2<<12) | (int)(__float_as_uint(S2) & 4095u);
      if (S1 - S2 < TAU){   // near-tie: exact fp32 rescore of both candidates
        float d1 = sqq[K1], d2 = sqq[K2];
        const float4* r1 = (const float4*)(cb + ((size_t)q*Kn + K1)*Cn);
        const float4* r2 = (const float4*)(cb + ((size_t)q*Kn + K2)*Cn);
#pragma unroll
        for (int g=0; g<16; ++g){
          float4 rv = RES4[tid*16 + (g ^ (tid&15))];
          float4 c1 = r1[g], c2 = r2[g];
          d1=fmaf(rv.x,c1.x,d1); d1=fmaf(rv.y,c1.y,d1);
          d1=fmaf(rv.z,c1.z,d1); d1=fmaf(rv.w,c1.w,d1);
          d2=fmaf(rv.x,c2.x,d2); d2=fmaf(rv.y,c2.y,d2);
          d2=fmaf(rv.z,c2.z,d2); d2=fmaf(rv.w,c2.w,d2);
        }
        if ( (d2 > d1) || (d2==d1 && K2<K1) ) K1 = K2;
      }
      bk_sh[tid]=K1;
      out[(size_t)(Bn*Cn*Nn) + (size_t)(b*Nn + n0 + tid)*Qn + q] = (float)K1;
    }
    __syncthreads();

    // ---- residual update (exact fp32, winner row L2-hot) + loss ----
    {
      int p = tid & (P-1), hc = tid>>6;    // hc in [0,4): 4 float4s each
      int bk = bk_sh[p];
      const float4* crow = (const float4*)(cb + ((size_t)q*Kn + bk)*Cn) + hc*4;
#pragma unroll
      for (int l=0;l<4;++l){
        int g = hc*4 + l;
        float4 v = crow[l];
        int idx = p*16 + (g ^ (p&15));
        float4 rv = RES4[idx];
        rv.x-=v.x; rv.y-=v.y; rv.z-=v.z; rv.w-=v.w;
        RES4[idx]=rv;
        loss_pt = fmaf(rv.x,rv.x,loss_pt); loss_pt = fmaf(rv.y,rv.y,loss_pt);
        loss_pt = fmaf(rv.z,rv.z,loss_pt); loss_pt = fmaf(rv.w,rv.w,loss_pt);
      }
    }
    __syncthreads();
  } // q

  // ---- quantized = x - final residual (coalesced over p) ----
#pragma unroll
  for (int it=0; it<4; ++it){
    int f = tid + it*256;
    int p = f & 63, g = f >> 6;
    const float* xb = x + ((size_t)b*Cn)*Nn + n0 + p;
    float*       ob = out + ((size_t)b*Cn)*Nn + n0 + p;
    float4 rv = RES4[p*16 + (g ^ (p&15))];
    ob[(size_t)(4*g+0)*Nn] = xb[(size_t)(4*g+0)*Nn] - rv.x;
    ob[(size_t)(4*g+1)*Nn] = xb[(size_t)(4*g+1)*Nn] - rv.y;
    ob[(size_t)(4*g+2)*Nn] = xb[(size_t)(4*g+2)*Nn] - rv.z;
    ob[(size_t)(4*g+3)*Nn] = xb[(size_t)(4*g+3)*Nn] - rv.w;
  }
  float s = loss_pt;
#pragma unroll
  for (int off=32; off>0; off>>=1) s += __shfl_down(s, off, 64);
  if (lane==0) lsum[wave]=s;
  __syncthreads();
  if (tid==0) atomicAdd(loss_acc, lsum[0]+lsum[1]+lsum[2]+lsum[3]);
}

__global__ void final_kernel(const float* __restrict__ loss_acc,
                             float* __restrict__ out){
  out[(size_t)Bn*Cn*Nn + (size_t)Bn*Nn*Qn] =
      loss_acc[0] * (1.0f / ((float)Qn * Bn * Nn * Cn));
}

extern "C" void kernel_launch(void* const* d_in, const int* in_sizes, int n_in,
                              void* d_out, int out_size, void* d_ws, size_t ws_size,
                              hipStream_t stream) {
  const float* x  = (const float*)d_in[0];
  const float* cb = (const float*)d_in[1];
  float* out = (float*)d_out;
  float* ws  = (float*)d_ws;

  float* shalf = ws;
  unsigned short* WH = (unsigned short*)(ws + SH_F);
  unsigned short* WL = WH + W_U;
  float* loss = (float*)(WL + W_U);

  hipLaunchKernelGGL(prep_kernel, dim3((Qn*Kn)/256), dim3(256), 0, stream,
                     cb, shalf, WH, WL, loss);
  hipLaunchKernelGGL(rvq_kernel, dim3(NBLK), dim3(256), 0, stream,
                     x, cb, shalf, WH, WL, out, loss);
  hipLaunchKernelGGL(final_kernel, dim3(1), dim3(1), 0, stream, loss, out);
}

// Round 9
// 3534.938 us; speedup vs baseline: 1.1070x; 1.1070x over previous
//
#include <hip/hip_runtime.h>
#include <float.h>

// RVQ inference via MFMA: B=16, C=64, N=4096, Q=8, K=8192, fp32 in/out.
// bf16 hi/lo split distance GEMM (hh+hl+lh, fp32 acc) on mfma_f32_16x16x32_bf16.
// Round-9: T=4 balance point. Evidence:
//  - R8 (T=2): L2-port-bound (16 waves x 5KB/ktile = 1463 cyc vs 932 matrix) -> 17%.
//  - R7 (T=8): VGPR 212 -> 2 waves/SIMD, latency bubbles -> 41%.
//  - T=4: matrix 466 cyc/ktile/wave vs 5KB loads; at 3-4 waves/SIMD port util
//    ~77%, load->use gap 466 cyc > L2 latency. VGPR ~130-150.
//  - 4-way k-split (2048 codes/wave), P=64 pts/block, grid 1024.
//  - __launch_bounds__(256,1): allocator meets demand, zero spills (R6/R7/R8).
//  - Packed-index top-2 (11-bit local k in mantissa LSBs, fmed3+fmax),
//    TAU=0.05 exact-fp32 rescore net (passed R5-R8).
// ws: shalf (QK f32) | WH (QKC bf16-hi u16) | WL (lo) | loss (f32).

typedef float f32x4 __attribute__((ext_vector_type(4)));
typedef short s16x8 __attribute__((ext_vector_type(8)));

constexpr int Bn=16, Cn=64, Nn=4096, Qn=8, Kn=8192;
constexpr int P=64;                     // points per block
constexpr int NBLK = Bn*Nn/P;           // 1024 blocks
constexpr float TAU = 0.05f;            // rescore margin
constexpr size_t SH_F = (size_t)Qn*Kn;
constexpr size_t W_U  = (size_t)Qn*Kn*Cn;

union U8 { s16x8 v; unsigned short u[8]; };

__device__ __forceinline__ unsigned short bf_rtne(float x){
  unsigned int u = __float_as_uint(x);
  unsigned int r = (u + 0x7fffu + ((u>>16)&1u)) >> 16;
  return (unsigned short)r;
}

__global__ __launch_bounds__(256) void prep_kernel(const float* __restrict__ cb,
    float* __restrict__ shalf, unsigned short* __restrict__ WH,
    unsigned short* __restrict__ WL, float* __restrict__ loss){
  int r = blockIdx.x*256 + threadIdx.x;
  if (r==0) *loss = 0.f;
  const float* row = cb + (size_t)r*Cn;
  float sq = 0.f;
  for (int c=0;c<Cn;++c){
    float v = row[c]; sq = fmaf(v,v,sq);
    unsigned short h = bf_rtne(v);
    float hf = __uint_as_float((unsigned int)h<<16);
    unsigned short l = bf_rtne(v-hf);
    WH[(size_t)r*Cn+c]=h; WL[(size_t)r*Cn+c]=l;
  }
  shalf[r] = -0.5f*sq;
}

#define LOADK(NK, H0,H1,L0,L1,SV) \
  H0 = *(const s16x8*)(WHq + (size_t)((NK)+l16)*Cn + quad*8); \
  H1 = *(const s16x8*)(WHq + (size_t)((NK)+l16)*Cn + 32 + quad*8); \
  L0 = *(const s16x8*)(WLq + (size_t)((NK)+l16)*Cn + quad*8); \
  L1 = *(const s16x8*)(WLq + (size_t)((NK)+l16)*Cn + 32 + quad*8); \
  SV = *(const f32x4*)(sqq + (NK) + kq);

#define COMPUTE(H0,H1,L0,L1,SV,KB) { \
  const unsigned kloc = (unsigned)((KB) & 2047) | (unsigned)kq; \
  _Pragma("unroll") \
  for (int pp=0; pp<2; ++pp){ \
    const int p0=2*pp, p1=2*pp+1; \
    f32x4 a0, a1; \
    a0 = __builtin_amdgcn_mfma_f32_16x16x32_bf16(H0, Bh[p0][0], SV, 0,0,0); \
    a1 = __builtin_amdgcn_mfma_f32_16x16x32_bf16(H0, Bh[p1][0], SV, 0,0,0); \
    a0 = __builtin_amdgcn_mfma_f32_16x16x32_bf16(H0, Bl[p0][0], a0, 0,0,0); \
    a1 = __builtin_amdgcn_mfma_f32_16x16x32_bf16(H0, Bl[p1][0], a1, 0,0,0); \
    a0 = __builtin_amdgcn_mfma_f32_16x16x32_bf16(L0, Bh[p0][0], a0, 0,0,0); \
    a1 = __builtin_amdgcn_mfma_f32_16x16x32_bf16(L0, Bh[p1][0], a1, 0,0,0); \
    a0 = __builtin_amdgcn_mfma_f32_16x16x32_bf16(H1, Bh[p0][1], a0, 0,0,0); \
    a1 = __builtin_amdgcn_mfma_f32_16x16x32_bf16(H1, Bh[p1][1], a1, 0,0,0); \
    a0 = __builtin_amdgcn_mfma_f32_16x16x32_bf16(H1, Bl[p0][1], a0, 0,0,0); \
    a1 = __builtin_amdgcn_mfma_f32_16x16x32_bf16(H1, Bl[p1][1], a1, 0,0,0); \
    a0 = __builtin_amdgcn_mfma_f32_16x16x32_bf16(L1, Bh[p0][1], a0, 0,0,0); \
    a1 = __builtin_amdgcn_mfma_f32_16x16x32_bf16(L1, Bh[p1][1], a1, 0,0,0); \
    _Pragma("unroll") \
    for (int r=0;r<4;++r){ \
      float pv0 = __uint_as_float((__float_as_uint(a0[r]) & 0xFFFFF800u) \
                                  | (kloc + (unsigned)r)); \
      float pv1 = __uint_as_float((__float_as_uint(a1[r]) & 0xFFFFF800u) \
                                  | (kloc + (unsigned)r)); \
      float n20 = __builtin_amdgcn_fmed3f(pv0, s1[p0], s2[p0]); \
      s1[p0] = fmaxf(s1[p0], pv0); s2[p0] = n20; \
      float n21 = __builtin_amdgcn_fmed3f(pv1, s1[p1], s2[p1]); \
      s1[p1] = fmaxf(s1[p1], pv1); s2[p1] = n21; \
    } \
  } }

__global__ __launch_bounds__(256,1)
void rvq_kernel(
    const float* __restrict__ x, const float* __restrict__ cb,
    const float* __restrict__ shalf,
    const unsigned short* __restrict__ WH, const unsigned short* __restrict__ WL,
    float* __restrict__ out, float* __restrict__ loss_acc){
  __shared__ float4 RES4[P*16];          // res[p][4g..] at [p*16 + (g^(p&15))]
  __shared__ float  red_p1[4][P];        // packed (score|k11) per wave
  __shared__ float  red_p2[4][P];
  __shared__ int    bk_sh[P];
  __shared__ float  lsum[4];

  const int tid  = threadIdx.x;
  const int wave = tid>>6, lane = tid&63;
  const int quad = lane>>4, l16 = lane&15;
  const int b    = blockIdx.x>>6;        // 64 blocks per batch elem
  const int n0   = (blockIdx.x&63)*P;

  { // ---- RES init from x[B,C,N] (coalesced over p) ----
#pragma unroll
    for (int it=0; it<4; ++it){
      int f = tid + it*256;              // 1024 float4s
      int p = f & 63, g = f >> 6;
      const float* xb = x + ((size_t)b*Cn)*Nn + n0 + p;
      float4 v;
      v.x = xb[(size_t)(4*g+0)*Nn]; v.y = xb[(size_t)(4*g+1)*Nn];
      v.z = xb[(size_t)(4*g+2)*Nn]; v.w = xb[(size_t)(4*g+3)*Nn];
      RES4[p*16 + (g ^ (p&15))] = v;
    }
  }
  __syncthreads();

  float loss_pt = 0.f;

  for (int q=0;q<Qn;++q){
    const unsigned short* WHq = WH + (size_t)q*Kn*Cn;
    const unsigned short* WLq = WL + (size_t)q*Kn*Cn;
    const float* sqq = shalf + (size_t)q*Kn;

    // ---- B-frags: 4 ptiles x 2 Khalves x hi/lo = 64 VGPRs, resident ----
    s16x8 Bh[4][2], Bl[4][2];
#pragma unroll
    for (int pt=0; pt<4; ++pt){
      int p = pt*16 + l16;
#pragma unroll
      for (int s=0;s<2;++s){
        int g0 = 8*s + quad*2;
        float4 ra = RES4[p*16 + ((g0  ) ^ (p&15))];
        float4 rb = RES4[p*16 + ((g0+1) ^ (p&15))];
        float f[8] = {ra.x,ra.y,ra.z,ra.w, rb.x,rb.y,rb.z,rb.w};
        U8 h, lo;
#pragma unroll
        for (int j=0;j<8;++j){
          unsigned short hu = bf_rtne(f[j]);
          float hf = __uint_as_float((unsigned int)hu<<16);
          h.u[j]=hu; lo.u[j]=bf_rtne(f[j]-hf);
        }
        Bh[pt][s]=h.v; Bl[pt][s]=lo.v;
      }
    }

    // ---- scan this wave's 2048-code quarter; packed top-2 per point ----
    float s1[4], s2[4];
#pragma unroll
    for (int pt=0;pt<4;++pt){ s1[pt]=-FLT_MAX; s2[pt]=-FLT_MAX; }

    const int kq = quad*4;
    const int kbase = wave*2048;
    s16x8 Ah0,Ah1,Al0,Al1; f32x4 sv;        // even-step regs
    s16x8 Xh0,Xh1,Xl0,Xl1; f32x4 xv;        // odd-step regs
    LOADK(kbase, Ah0,Ah1,Al0,Al1,sv)

    for (int kt2=0; kt2<64; ++kt2){
      const int ka = kbase + (kt2*2+1)*16;            // odd ktile (always valid)
      LOADK(ka, Xh0,Xh1,Xl0,Xl1,xv)
      COMPUTE(Ah0,Ah1,Al0,Al1,sv, kbase + kt2*2*16)
      const int kbn = kbase + ((kt2*2+2) & 127)*16;   // next even (wraps at end)
      LOADK(kbn, Ah0,Ah1,Al0,Al1,sv)
      COMPUTE(Xh0,Xh1,Xl0,Xl1,xv, ka)
    }

    // ---- cross-quad top-2 merge in packed domain ----
#pragma unroll
    for (int pt=0;pt<4;++pt){
#pragma unroll
      for (int m=16; m<=32; m<<=1){
        float o1 = __shfl_xor(s1[pt], m, 64);
        float o2 = __shfl_xor(s2[pt], m, 64);
        float n1 = fmaxf(s1[pt], o1);
        float n2 = fmaxf(fminf(s1[pt], o1), fmaxf(s2[pt], o2));
        s1[pt]=n1; s2[pt]=n2;
      }
      if (quad==0){
        red_p1[wave][pt*16 + l16] = s1[pt];
        red_p2[wave][pt*16 + l16] = s2[pt];
      }
    }
    __syncthreads();

    // ---- per-point 4-wave merge (track wave origin) + margin rescore ----
    if (tid < P){
      float S1 = red_p1[0][tid]; int W1 = 0;
      float S2 = red_p2[0][tid]; int W2 = 0;
#pragma unroll
      for (int w=1; w<4; ++w){
        float o1 = red_p1[w][tid], o2 = red_p2[w][tid];
        if (o1 > S1){
          if (S1 > o2){ S2 = S1; W2 = W1; } else { S2 = o2; W2 = w; }
          S1 = o1; W1 = w;
        } else if (o1 > S2){ S2 = o1; W2 = w; }
      }
      int K1 = (W1<<11) | (int)(__float_as_uint(S1) & 2047u);
      int K2 = (W2<<11) | (int)(__float_as_uint(S2) & 2047u);
      if (S1 - S2 < TAU){   // near-tie: exact fp32 rescore of both candidates
        float d1 = sqq[K1], d2 = sqq[K2];
        const float4* r1 = (const float4*)(cb + ((size_t)q*Kn + K1)*Cn);
        const float4* r2 = (const float4*)(cb + ((size_t)q*Kn + K2)*Cn);
#pragma unroll
        for (int g=0; g<16; ++g){
          float4 rv = RES4[tid*16 + (g ^ (tid&15))];
          float4 c1 = r1[g], c2 = r2[g];
          d1=fmaf(rv.x,c1.x,d1); d1=fmaf(rv.y,c1.y,d1);
          d1=fmaf(rv.z,c1.z,d1); d1=fmaf(rv.w,c1.w,d1);
          d2=fmaf(rv.x,c2.x,d2); d2=fmaf(rv.y,c2.y,d2);
          d2=fmaf(rv.z,c2.z,d2); d2=fmaf(rv.w,c2.w,d2);
        }
        if ( (d2 > d1) || (d2==d1 && K2<K1) ) K1 = K2;
      }
      bk_sh[tid]=K1;
      out[(size_t)(Bn*Cn*Nn) + (size_t)(b*Nn + n0 + tid)*Qn + q] = (float)K1;
    }
    __syncthreads();

    // ---- residual update (exact fp32, winner row L2-hot) + loss ----
    {
      int p = tid & (P-1), hc = tid>>6;    // hc in [0,4): 4 float4s each
      int bk = bk_sh[p];
      const float4* crow = (const float4*)(cb + ((size_t)q*Kn + bk)*Cn) + hc*4;
#pragma unroll
      for (int l=0;l<4;++l){
        int g = hc*4 + l;
        float4 v = crow[l];
        int idx = p*16 + (g ^ (p&15));
        float4 rv = RES4[idx];
        rv.x-=v.x; rv.y-=v.y; rv.z-=v.z; rv.w-=v.w;
        RES4[idx]=rv;
        loss_pt = fmaf(rv.x,rv.x,loss_pt); loss_pt = fmaf(rv.y,rv.y,loss_pt);
        loss_pt = fmaf(rv.z,rv.z,loss_pt); loss_pt = fmaf(rv.w,rv.w,loss_pt);
      }
    }
    __syncthreads();
  } // q

  // ---- quantized = x - final residual (coalesced over p) ----
#pragma unroll
  for (int it=0; it<4; ++it){
    int f = tid + it*256;
    int p = f & 63, g = f >> 6;
    const float* xb = x + ((size_t)b*Cn)*Nn + n0 + p;
    float*       ob = out + ((size_t)b*Cn)*Nn + n0 + p;
    float4 rv = RES4[p*16 + (g ^ (p&15))];
    ob[(size_t)(4*g+0)*Nn] = xb[(size_t)(4*g+0)*Nn] - rv.x;
    ob[(size_t)(4*g+1)*Nn] = xb[(size_t)(4*g+1)*Nn] - rv.y;
    ob[(size_t)(4*g+2)*Nn] = xb[(size_t)(4*g+2)*Nn] - rv.z;
    ob[(size_t)(4*g+3)*Nn] = xb[(size_t)(4*g+3)*Nn] - rv.w;
  }
  float s = loss_pt;
#pragma unroll
  for (int off=32; off>0; off>>=1) s += __shfl_down(s, off, 64);
  if (lane==0) lsum[wave]=s;
  __syncthreads();
  if (tid==0) atomicAdd(loss_acc, lsum[0]+lsum[1]+lsum[2]+lsum[3]);
}

__global__ void final_kernel(const float* __restrict__ loss_acc,
                             float* __restrict__ out){
  out[(size_t)Bn*Cn*Nn + (size_t)Bn*Nn*Qn] =
      loss_acc[0] * (1.0f / ((float)Qn * Bn * Nn * Cn));
}

extern "C" void kernel_launch(void* const* d_in, const int* in_sizes, int n_in,
                              void* d_out, int out_size, void* d_ws, size_t ws_size,
                              hipStream_t stream) {
  const float* x  = (const float*)d_in[0];
  const float* cb = (const float*)d_in[1];
  float* out = (float*)d_out;
  float* ws  = (float*)d_ws;

  float* shalf = ws;
  unsigned short* WH = (unsigned short*)(ws + SH_F);
  unsigned short* WL = WH + W_U;
  float* loss = (float*)(WL + W_U);

  hipLaunchKernelGGL(prep_kernel, dim3((Qn*Kn)/256), dim3(256), 0, stream,
                     cb, shalf, WH, WL, loss);
  hipLaunchKernelGGL(rvq_kernel, dim3(NBLK), dim3(256), 0, stream,
                     x, cb, shalf, WH, WL, out, loss);
  hipLaunchKernelGGL(final_kernel, dim3(1), dim3(1), 0, stream, loss, out);
}

// Round 10
// 2485.377 us; speedup vs baseline: 1.5745x; 1.4223x over previous
//
#include <hip/hip_runtime.h>
#include <float.h>

// RVQ inference via MFMA: B=16, C=64, N=4096, Q=8, K=8192, fp32 in/out.
// Round-10: switch to mfma_f32_32x32x16_bf16 (2382 TF vs 2075 -> floor 693us;
// half the A-bytes and B-regs per point of the 16x16 shape).
//  - P=64 pts/block, 4 waves k-split (2048 codes each), T'=2 point-tiles/wave.
//  - hi/lo bf16 3-product (hh+lh+hl) per 16-ch chunk: 12 MFMA per 32-code ktile
//    per tile; acc C-init from -0.5|c|^2 (sv tuple, shared by both tiles).
//  - Packed top-2: 10-bit scalar field (kt*16+reg)<<1 per score (1 v_and_or,
//    SGPR src2), h-bit OR'd once per q before the lane-pair merge; TAU=0.05
//    exact-fp32 rescore net (passed R5-R9) absorbs pack noise + ties.
//  - __launch_bounds__(256,1): allocator meets demand, zero spills (R6-R9).
// A layout (32x32x16): lane l holds A[row=l&31][k=8*(l>>5)+j]; B analogous;
// C/D: col=lane&31, row=(r&3)+8*(r>>2)+4*(lane>>5)  [m74/m101-verified].
// ws: shalf (QK f32) | WH (QKC bf16-hi u16) | WL (lo) | loss (f32).

typedef float f32x4  __attribute__((ext_vector_type(4)));
typedef float f32x16 __attribute__((ext_vector_type(16)));
typedef short s16x8  __attribute__((ext_vector_type(8)));

constexpr int Bn=16, Cn=64, Nn=4096, Qn=8, Kn=8192;
constexpr int P=64;                     // points per block
constexpr int NBLK = Bn*Nn/P;           // 1024 blocks
constexpr float TAU = 0.05f;            // rescore margin
constexpr size_t SH_F = (size_t)Qn*Kn;
constexpr size_t W_U  = (size_t)Qn*Kn*Cn;

union U8 { s16x8 v; unsigned short u[8]; };
union SV16 { f32x16 v; f32x4 q[4]; };

__device__ __forceinline__ unsigned short bf_rtne(float x){
  unsigned int u = __float_as_uint(x);
  unsigned int r = (u + 0x7fffu + ((u>>16)&1u)) >> 16;
  return (unsigned short)r;
}

__global__ __launch_bounds__(256) void prep_kernel(const float* __restrict__ cb,
    float* __restrict__ shalf, unsigned short* __restrict__ WH,
    unsigned short* __restrict__ WL, float* __restrict__ loss){
  int r = blockIdx.x*256 + threadIdx.x;
  if (r==0) *loss = 0.f;
  const float* row = cb + (size_t)r*Cn;
  float sq = 0.f;
  for (int c=0;c<Cn;++c){
    float v = row[c]; sq = fmaf(v,v,sq);
    unsigned short h = bf_rtne(v);
    float hf = __uint_as_float((unsigned int)h<<16);
    unsigned short l = bf_rtne(v-hf);
    WH[(size_t)r*Cn+c]=h; WL[(size_t)r*Cn+c]=l;
  }
  shalf[r] = -0.5f*sq;
}

__global__ __launch_bounds__(256,1)
void rvq_kernel(
    const float* __restrict__ x, const float* __restrict__ cb,
    const float* __restrict__ shalf,
    const unsigned short* __restrict__ WH, const unsigned short* __restrict__ WL,
    float* __restrict__ out, float* __restrict__ loss_acc){
  __shared__ float4 RES4[P*16];          // res[p][4g..] at [p*16 + (g^(p&15))]
  __shared__ float  red_p1[4][P];        // packed (score|k11) per wave
  __shared__ float  red_p2[4][P];
  __shared__ int    bk_sh[P];
  __shared__ float  lsum[4];

  const int tid  = threadIdx.x;
  const int wave = tid>>6, lane = tid&63;
  const int c5   = lane & 31;            // point/code column
  const int h5   = lane >> 5;            // lane half
  const int b    = blockIdx.x>>6;        // 64 blocks per batch elem
  const int n0   = (blockIdx.x&63)*P;

  { // ---- RES init from x[B,C,N] (coalesced over p) ----
#pragma unroll
    for (int it=0; it<4; ++it){
      int f = tid + it*256;              // 1024 float4s
      int p = f & 63, g = f >> 6;
      const float* xb = x + ((size_t)b*Cn)*Nn + n0 + p;
      float4 v;
      v.x = xb[(size_t)(4*g+0)*Nn]; v.y = xb[(size_t)(4*g+1)*Nn];
      v.z = xb[(size_t)(4*g+2)*Nn]; v.w = xb[(size_t)(4*g+3)*Nn];
      RES4[p*16 + (g ^ (p&15))] = v;
    }
  }
  __syncthreads();

  float loss_pt = 0.f;
  const unsigned vmask = 0xFFFFF800u;    // keep in VGPR so idx can be SGPR

  for (int q=0;q<Qn;++q){
    const unsigned short* WHq = WH + (size_t)q*Kn*Cn;
    const unsigned short* WLq = WL + (size_t)q*Kn*Cn;
    const float* sqq = shalf + (size_t)q*Kn;

    // ---- B-frags: 2 tiles x 4 k-chunks x hi/lo = 64 VGPRs, resident ----
    s16x8 Bh[2][4], Bl[2][4];
#pragma unroll
    for (int t=0; t<2; ++t){
      int p = t*32 + c5;
#pragma unroll
      for (int kc=0; kc<4; ++kc){
        int g0 = 4*kc + 2*h5;            // ch = kc*16 + 8*h5 + j
        float4 ra = RES4[p*16 + ((g0  ) ^ (p&15))];
        float4 rb = RES4[p*16 + ((g0+1) ^ (p&15))];
        float f[8] = {ra.x,ra.y,ra.z,ra.w, rb.x,rb.y,rb.z,rb.w};
        U8 h, lo;
#pragma unroll
        for (int j=0;j<8;++j){
          unsigned short hu = bf_rtne(f[j]);
          float hf = __uint_as_float((unsigned int)hu<<16);
          h.u[j]=hu; lo.u[j]=bf_rtne(f[j]-hf);
        }
        Bh[t][kc]=h.v; Bl[t][kc]=lo.v;
      }
    }

    // ---- scan this wave's 2048-code quarter; packed top-2 per point ----
    float s1[2], s2[2];
    s1[0]=-FLT_MAX; s2[0]=-FLT_MAX; s1[1]=-FLT_MAX; s2[1]=-FLT_MAX;

    const int kb0 = wave*2048;
#pragma unroll 2
    for (int kt=0; kt<64; ++kt){
      const int kb  = kb0 + kt*32;
      const int row = kb + c5;
      const unsigned short* ah = WHq + (size_t)row*Cn + 8*h5;
      const unsigned short* al = WLq + (size_t)row*Cn + 8*h5;
      s16x8 Ah0 = *(const s16x8*)(ah);
      s16x8 Ah1 = *(const s16x8*)(ah+16);
      s16x8 Ah2 = *(const s16x8*)(ah+32);
      s16x8 Ah3 = *(const s16x8*)(ah+48);
      s16x8 Al0 = *(const s16x8*)(al);
      s16x8 Al1 = *(const s16x8*)(al+16);
      s16x8 Al2 = *(const s16x8*)(al+32);
      s16x8 Al3 = *(const s16x8*)(al+48);
      const float* svp = sqq + kb + 4*h5;  // rows 8g'+4h+0..3 for reg-group g'
      SV16 sv;
      sv.q[0] = *(const f32x4*)(svp);
      sv.q[1] = *(const f32x4*)(svp+8);
      sv.q[2] = *(const f32x4*)(svp+16);
      sv.q[3] = *(const f32x4*)(svp+24);

      const int sb = kt*32;              // packed field base: (kt*16+r)<<1
#pragma unroll
      for (int t=0;t<2;++t){
        f32x16 a;
        a = __builtin_amdgcn_mfma_f32_32x32x16_bf16(Ah0, Bh[t][0], sv.v, 0,0,0);
        a = __builtin_amdgcn_mfma_f32_32x32x16_bf16(Al0, Bh[t][0], a, 0,0,0);
        a = __builtin_amdgcn_mfma_f32_32x32x16_bf16(Ah0, Bl[t][0], a, 0,0,0);
        a = __builtin_amdgcn_mfma_f32_32x32x16_bf16(Ah1, Bh[t][1], a, 0,0,0);
        a = __builtin_amdgcn_mfma_f32_32x32x16_bf16(Al1, Bh[t][1], a, 0,0,0);
        a = __builtin_amdgcn_mfma_f32_32x32x16_bf16(Ah1, Bl[t][1], a, 0,0,0);
        a = __builtin_amdgcn_mfma_f32_32x32x16_bf16(Ah2, Bh[t][2], a, 0,0,0);
        a = __builtin_amdgcn_mfma_f32_32x32x16_bf16(Al2, Bh[t][2], a, 0,0,0);
        a = __builtin_amdgcn_mfma_f32_32x32x16_bf16(Ah2, Bl[t][2], a, 0,0,0);
        a = __builtin_amdgcn_mfma_f32_32x32x16_bf16(Ah3, Bh[t][3], a, 0,0,0);
        a = __builtin_amdgcn_mfma_f32_32x32x16_bf16(Al3, Bh[t][3], a, 0,0,0);
        a = __builtin_amdgcn_mfma_f32_32x32x16_bf16(Ah3, Bl[t][3], a, 0,0,0);
#pragma unroll
        for (int j=0;j<8;++j){
          // pack: 1 v_and_or per score (idx is wave-uniform -> SGPR src2)
          float p0 = __uint_as_float((__float_as_uint(a[2*j  ]) & vmask)
                                     | (unsigned)(sb + 4*j    ));
          float p1 = __uint_as_float((__float_as_uint(a[2*j+1]) & vmask)
                                     | (unsigned)(sb + 4*j + 2));
          // merged top-2: s2 = max(s2, med3(p0,p1,s1)); s1 = max3(s1,p0,p1)
          s2[t] = fmaxf(s2[t], __builtin_amdgcn_fmed3f(p0, p1, s1[t]));
          s1[t] = fmaxf(fmaxf(s1[t], p0), p1);
        }
      }
    }

    // ---- OR in the lane-half bit, merge lane pairs (l, l^32) ----
#pragma unroll
    for (int t=0;t<2;++t){
      s1[t] = __uint_as_float(__float_as_uint(s1[t]) | (unsigned)h5);
      s2[t] = __uint_as_float(__float_as_uint(s2[t]) | (unsigned)h5);
      float o1 = __shfl_xor(s1[t], 32, 64);
      float o2 = __shfl_xor(s2[t], 32, 64);
      float n1 = fmaxf(s1[t], o1);
      float n2 = fmaxf(fminf(s1[t], o1), fmaxf(s2[t], o2));
      s1[t]=n1; s2[t]=n2;
      if (h5==0){
        red_p1[wave][t*32 + c5] = s1[t];
        red_p2[wave][t*32 + c5] = s2[t];
      }
    }
    __syncthreads();

    // ---- per-point 4-wave merge (track wave origin) + margin rescore ----
    if (tid < P){
      float S1 = red_p1[0][tid]; int W1 = 0;
      float S2 = red_p2[0][tid]; int W2 = 0;
#pragma unroll
      for (int w=1; w<4; ++w){
        float o1 = red_p1[w][tid], o2 = red_p2[w][tid];
        if (o1 > S1){
          if (S1 > o2){ S2 = S1; W2 = W1; } else { S2 = o2; W2 = w; }
          S1 = o1; W1 = w;
        } else if (o1 > S2){ S2 = o1; W2 = w; }
      }
      // decode 11-bit field: f = ((kt*16 + r)<<1) | h
      int f1 = (int)(__float_as_uint(S1) & 2047u);
      int v1 = f1>>1;
      int K1 = W1*2048 + (v1>>4)*32 + ((v1>>2)&3)*8 + (f1&1)*4 + (v1&3);
      int f2 = (int)(__float_as_uint(S2) & 2047u);
      int v2 = f2>>1;
      int K2 = W2*2048 + (v2>>4)*32 + ((v2>>2)&3)*8 + (f2&1)*4 + (v2&3);
      if (S1 - S2 < TAU){   // near-tie: exact fp32 rescore of both candidates
        float d1 = sqq[K1], d2 = sqq[K2];
        const float4* r1 = (const float4*)(cb + ((size_t)q*Kn + K1)*Cn);
        const float4* r2 = (const float4*)(cb + ((size_t)q*Kn + K2)*Cn);
#pragma unroll
        for (int g=0; g<16; ++g){
          float4 rv = RES4[tid*16 + (g ^ (tid&15))];
          float4 c1 = r1[g], c2 = r2[g];
          d1=fmaf(rv.x,c1.x,d1); d1=fmaf(rv.y,c1.y,d1);
          d1=fmaf(rv.z,c1.z,d1); d1=fmaf(rv.w,c1.w,d1);
          d2=fmaf(rv.x,c2.x,d2); d2=fmaf(rv.y,c2.y,d2);
          d2=fmaf(rv.z,c2.z,d2); d2=fmaf(rv.w,c2.w,d2);
        }
        if ( (d2 > d1) || (d2==d1 && K2<K1) ) K1 = K2;
      }
      bk_sh[tid]=K1;
      out[(size_t)(Bn*Cn*Nn) + (size_t)(b*Nn + n0 + tid)*Qn + q] = (float)K1;
    }
    __syncthreads();

    // ---- residual update (exact fp32, winner row L2-hot) + loss ----
    {
      int p = tid & (P-1), hc = tid>>6;    // hc in [0,4): 4 float4s each
      int bk = bk_sh[p];
      const float4* crow = (const float4*)(cb + ((size_t)q*Kn + bk)*Cn) + hc*4;
#pragma unroll
      for (int l=0;l<4;++l){
        int g = hc*4 + l;
        float4 v = crow[l];
        int idx = p*16 + (g ^ (p&15));
        float4 rv = RES4[idx];
        rv.x-=v.x; rv.y-=v.y; rv.z-=v.z; rv.w-=v.w;
        RES4[idx]=rv;
        loss_pt = fmaf(rv.x,rv.x,loss_pt); loss_pt = fmaf(rv.y,rv.y,loss_pt);
        loss_pt = fmaf(rv.z,rv.z,loss_pt); loss_pt = fmaf(rv.w,rv.w,loss_pt);
      }
    }
    __syncthreads();
  } // q

  // ---- quantized = x - final residual (coalesced over p) ----
#pragma unroll
  for (int it=0; it<4; ++it){
    int f = tid + it*256;
    int p = f & 63, g = f >> 6;
    const float* xb = x + ((size_t)b*Cn)*Nn + n0 + p;
    float*       ob = out + ((size_t)b*Cn)*Nn + n0 + p;
    float4 rv = RES4[p*16 + (g ^ (p&15))];
    ob[(size_t)(4*g+0)*Nn] = xb[(size_t)(4*g+0)*Nn] - rv.x;
    ob[(size_t)(4*g+1)*Nn] = xb[(size_t)(4*g+1)*Nn] - rv.y;
    ob[(size_t)(4*g+2)*Nn] = xb[(size_t)(4*g+2)*Nn] - rv.z;
    ob[(size_t)(4*g+3)*Nn] = xb[(size_t)(4*g+3)*Nn] - rv.w;
  }
  float s = loss_pt;
#pragma unroll
  for (int off=32; off>0; off>>=1) s += __shfl_down(s, off, 64);
  if (lane==0) lsum[wave]=s;
  __syncthreads();
  if (tid==0) atomicAdd(loss_acc, lsum[0]+lsum[1]+lsum[2]+lsum[3]);
}

__global__ void final_kernel(const float* __restrict__ loss_acc,
                             float* __restrict__ out){
  out[(size_t)Bn*Cn*Nn + (size_t)Bn*Nn*Qn] =
      loss_acc[0] * (1.0f / ((float)Qn * Bn * Nn * Cn));
}

extern "C" void kernel_launch(void* const* d_in, const int* in_sizes, int n_in,
                              void* d_out, int out_size, void* d_ws, size_t ws_size,
                              hipStream_t stream) {
  const float* x  = (const float*)d_in[0];
  const float* cb = (const float*)d_in[1];
  float* out = (float*)d_out;
  float* ws  = (float*)d_ws;

  float* shalf = ws;
  unsigned short* WH = (unsigned short*)(ws + SH_F);
  unsigned short* WL = WH + W_U;
  float* loss = (float*)(WL + W_U);

  hipLaunchKernelGGL(prep_kernel, dim3((Qn*Kn)/256), dim3(256), 0, stream,
                     cb, shalf, WH, WL, loss);
  hipLaunchKernelGGL(rvq_kernel, dim3(NBLK), dim3(256), 0, stream,
                     x, cb, shalf, WH, WL, out, loss);
  hipLaunchKernelGGL(final_kernel, dim3(1), dim3(1), 0, stream, loss, out);
}